// Round 25
// baseline (186.316 us; speedup 1.0000x reference)
//
#include <hip/hip_runtime.h>
#include <hip/hip_bf16.h>
#include <stdint.h>

typedef unsigned short u16;
typedef unsigned int u32;
typedef unsigned long long u64;
typedef __attribute__((ext_vector_type(8))) short bf16x8;
typedef __attribute__((ext_vector_type(4))) float f32x4;
typedef __attribute__((ext_vector_type(4))) u32 u32x4;

#define NB 2
#define NH 16
#define TT 2048
#define DD 64
#define CC 1024

__device__ __forceinline__ u16 bf16bits(float f) {
    __hip_bfloat16 h = __float2bfloat16(f);
    return __builtin_bit_cast(unsigned short, h);
}

__device__ __forceinline__ void gload_lds16(const void* g, void* l) {
    __builtin_amdgcn_global_load_lds(
        (const __attribute__((address_space(1))) void*)g,
        (__attribute__((address_space(3))) void*)l, 16, 0, 0);
}

// ---------------- fused prep: f32->bf16 converts + causal-clipped mask bits --
__global__ __launch_bounds__(256) void prep_all(
    const float* __restrict__ x, const float* __restrict__ Wa_f,
    const float* __restrict__ Wp_f, const float* __restrict__ ml,
    u16* __restrict__ xb, u16* __restrict__ wab, u16* __restrict__ wpb,
    unsigned char* __restrict__ mb) {
    const int bid = blockIdx.x;
    if (bid < 512) {
        int idx = bid * 256 + threadIdx.x;
        for (int i = idx; i < 2097152; i += 512 * 256) {
            const float* src; u16* dst; int off;
            if (i < 1048576)      { src = x;    dst = xb;  off = i; }
            else if (i < 1835008) { src = Wa_f; dst = wab; off = i - 1048576; }
            else                  { src = Wp_f; dst = wpb; off = i - 1835008; }
            float4 v = reinterpret_cast<const float4*>(src)[off];
            ushort4 o;
            o.x = bf16bits(v.x); o.y = bf16bits(v.y);
            o.z = bf16bits(v.z); o.w = bf16bits(v.w);
            reinterpret_cast<ushort4*>(dst)[off] = o;
        }
    } else {
        const int wid = ((bid - 512) << 2) + (threadIdx.x >> 6);  // 0..4095
        const int lane = threadIdx.x & 63;
        const int i0 = wid & 2047;
        const int hbase = (wid >> 11) << 3;  // 0 or 8
#pragma unroll 1
        for (int k = 0; k < 8; ++k) {
            int h = hbase + k;
            int i = (k & 1) ? (2047 - i0) : i0;
            int row = h * 2048 + i;
            const float* src = ml + (size_t)row * TT;
            unsigned char* dst = mb + (size_t)row * (TT / 8);
#pragma unroll 1
            for (int c8 = lane; c8 < 256; c8 += 64) {
                unsigned char v = 0;
                if (c8 * 8 <= i) {
                    const float4* p = reinterpret_cast<const float4*>(src + c8 * 8);
                    float4 a = p[0];
                    float4 b = p[1];
                    unsigned u = 0;
                    u |= (a.x > 0.f) ? 1u : 0u;
                    u |= (a.y > 0.f) ? 2u : 0u;
                    u |= (a.z > 0.f) ? 4u : 0u;
                    u |= (a.w > 0.f) ? 8u : 0u;
                    u |= (b.x > 0.f) ? 16u : 0u;
                    u |= (b.y > 0.f) ? 32u : 0u;
                    u |= (b.z > 0.f) ? 64u : 0u;
                    u |= (b.w > 0.f) ? 128u : 0u;
                    int rem = i - c8 * 8;
                    if (rem < 7) u &= (1u << (rem + 1)) - 1;  // causal clip
                    v = (unsigned char)u;
                }
                dst[c8] = v;
            }
        }
    }
}

// ---------------- QKV GEMM (128x128 tile) ------------------------------------
__global__ __launch_bounds__(256) void gemm_qkv(
    const u16* __restrict__ A, const u16* __restrict__ Bw,
    const float* __restrict__ bias,
    u16* __restrict__ Qb, u16* __restrict__ Kb, u16* __restrict__ Vtb) {
    const int bm = blockIdx.y * 128;
    const int bn = blockIdx.x * 128;
    const int tid = threadIdx.x;
    const int w = tid >> 6, lane = tid & 63;
    const int lrow = lane & 15, lgrp = lane >> 4;
    const int wr = (w >> 1) * 64, wc = (w & 1) * 64;

    __shared__ __align__(16) u16 ABs[2][128 * 64];
    u16* As = ABs[0];
    u16* Bs = ABs[1];

    f32x4 acc[4][4] = {};

    for (int kt = 0; kt < 16; ++kt) {
        const int k0 = kt << 6;
#pragma unroll
        for (int i = 0; i < 4; ++i) {
            int e = i * 2048 + tid * 8;
            int r = e >> 6, c = e & 63;
            gload_lds16(A + (size_t)(bm + r) * CC + k0 + c, (char*)As + i * 4096 + w * 1024);
            gload_lds16(Bw + (size_t)(bn + r) * CC + k0 + c, (char*)Bs + i * 4096 + w * 1024);
        }
        __syncthreads();
#pragma unroll
        for (int kk = 0; kk < 2; ++kk) {
            bf16x8 af[4], bfz[4];
#pragma unroll
            for (int i = 0; i < 4; ++i)
                af[i] = *reinterpret_cast<const bf16x8*>(&As[(wr + i * 16 + lrow) * 64 + kk * 32 + lgrp * 8]);
#pragma unroll
            for (int i = 0; i < 4; ++i)
                bfz[i] = *reinterpret_cast<const bf16x8*>(&Bs[(wc + i * 16 + lrow) * 64 + kk * 32 + lgrp * 8]);
#pragma unroll
            for (int mi = 0; mi < 4; ++mi)
#pragma unroll
                for (int ni = 0; ni < 4; ++ni)
                    acc[mi][ni] = __builtin_amdgcn_mfma_f32_16x16x32_bf16(af[mi], bfz[ni], acc[mi][ni], 0, 0, 0);
        }
        __syncthreads();
    }

    const int sec = bn >> 10;

    if (sec == 2) {
        // ---- V epilogue: LDS transpose for coalesced Vt writes ----
        u16* Tl = &ABs[0][0];
#pragma unroll
        for (int ni = 0; ni < 4; ++ni) {
            int nl = wc + ni * 16 + lrow;
            float bv = bias[bn + nl];
#pragma unroll
            for (int mi = 0; mi < 4; ++mi) {
                int ml2 = wr + mi * 16 + lgrp * 4;
                u64 pk = 0;
#pragma unroll
                for (int j = 0; j < 4; ++j)
                    pk |= (u64)bf16bits(acc[mi][ni][j] + bv) << (16 * j);
                int byte = nl * 256 + ((ml2 * 2) ^ ((nl & 7) << 4));
                *reinterpret_cast<u64*>((char*)Tl + byte) = pk;
            }
        }
        __syncthreads();
        int r = tid >> 1, half = tid & 1;
        int h = ((bn & 1023) >> 6) + (r >> 6);
        int d = r & 63;
        int b = bm >> 11;
        u16* gdst = Vtb + (((size_t)b * NH + h) * DD + d) * TT + (bm & 2047) + half * 64;
#pragma unroll
        for (int c = 0; c < 8; ++c) {
            uint4 v = *reinterpret_cast<const uint4*>(
                (char*)Tl + r * 256 + ((half * 128 + c * 16) ^ ((r & 7) << 4)));
            *reinterpret_cast<uint4*>(gdst + c * 8) = v;
        }
        return;
    }

#pragma unroll
    for (int ni = 0; ni < 4; ++ni) {
        int n = bn + wc + ni * 16 + lrow;
        float bv = bias[n];
#pragma unroll
        for (int mi = 0; mi < 4; ++mi) {
#pragma unroll
            for (int j = 0; j < 4; ++j) {
                int m = bm + wr + mi * 16 + lgrp * 4 + j;
                float v = acc[mi][ni][j] + bv;
                int h = (n & 1023) >> 6;
                int d = n & 63;
                int b = m >> 11;
                int t = m & 2047;
                if (sec == 0) {
                    // fold 1/sqrt(64) and log2(e): softmax runs in exp2 domain
                    Qb[(((size_t)b * NH + h) * TT + t) * DD + d] =
                        bf16bits(v * (0.125f * 1.4426950408889634f));
                } else {
                    Kb[(((size_t)b * NH + h) * TT + t) * DD + d] = bf16bits(v);
                }
            }
        }
    }
}

// ---------------- proj GEMM (64x128 tile, 512 blocks = 2/CU) -----------------
__global__ __launch_bounds__(256) void gemm_proj(
    const u16* __restrict__ A, const u16* __restrict__ Bw,
    const float* __restrict__ bias, float* __restrict__ Cout) {
    const int bm = blockIdx.y * 64;
    const int bn = blockIdx.x * 128;
    const int tid = threadIdx.x;
    const int w = tid >> 6, lane = tid & 63;
    const int lrow = lane & 15, lgrp = lane >> 4;
    const int wr = (w >> 1) * 32, wc = (w & 1) * 64;

    __shared__ __align__(16) u16 As[64 * 64];    // 8 KB
    __shared__ __align__(16) u16 Bs[128 * 64];   // 16 KB

    f32x4 acc[2][4] = {};

    for (int kt = 0; kt < 16; ++kt) {
        const int k0 = kt << 6;
#pragma unroll
        for (int i = 0; i < 2; ++i) {
            int e = i * 2048 + tid * 8;
            int r = e >> 6, c = e & 63;
            gload_lds16(A + (size_t)(bm + r) * CC + k0 + c, (char*)As + i * 4096 + w * 1024);
        }
#pragma unroll
        for (int i = 0; i < 4; ++i) {
            int e = i * 2048 + tid * 8;
            int r = e >> 6, c = e & 63;
            gload_lds16(Bw + (size_t)(bn + r) * CC + k0 + c, (char*)Bs + i * 4096 + w * 1024);
        }
        __syncthreads();
#pragma unroll
        for (int kk = 0; kk < 2; ++kk) {
            bf16x8 af[2], bfz[4];
#pragma unroll
            for (int i = 0; i < 2; ++i)
                af[i] = *reinterpret_cast<const bf16x8*>(&As[(wr + i * 16 + lrow) * 64 + kk * 32 + lgrp * 8]);
#pragma unroll
            for (int i = 0; i < 4; ++i)
                bfz[i] = *reinterpret_cast<const bf16x8*>(&Bs[(wc + i * 16 + lrow) * 64 + kk * 32 + lgrp * 8]);
#pragma unroll
            for (int mi = 0; mi < 2; ++mi)
#pragma unroll
                for (int ni = 0; ni < 4; ++ni)
                    acc[mi][ni] = __builtin_amdgcn_mfma_f32_16x16x32_bf16(af[mi], bfz[ni], acc[mi][ni], 0, 0, 0);
        }
        __syncthreads();
    }

#pragma unroll
    for (int ni = 0; ni < 4; ++ni) {
        int n = bn + wc + ni * 16 + lrow;
        float bv = bias[n];
#pragma unroll
        for (int mi = 0; mi < 2; ++mi) {
#pragma unroll
            for (int j = 0; j < 4; ++j) {
                int m = bm + wr + mi * 16 + lgrp * 4 + j;
                Cout[(size_t)m * 1024 + n] = acc[mi][ni][j] + bv;
            }
        }
    }
}

// ---------------- fused masked flash attention, parity-split -----------------
// Waves {0,1} process EVEN k-tiles, {2,3} ODD k-tiles; each wave owns 32 q-rows
// (2 groups) so K/V fragments are read ONCE per active tile and reused for both
// groups -> CU LDS reads per k-tile halve (64->32 b128). Static-max softmax
// makes parity partials directly summable (one-time LDS combine at the end,
// reusing the dead Ks/Vts buffers). T12 in-register P redistribution; grid,
// LDS (32KB), and 16 waves/CU occupancy unchanged.
// grid: (512 = slot*16+h, 2 batches); block 256 = 4 waves, one 64-row q-tile.
__global__ __launch_bounds__(256) void attn_kernel(
    const u16* __restrict__ Qb, const u16* __restrict__ Kb,
    const u16* __restrict__ Vtb, const unsigned char* __restrict__ mb,
    u16* __restrict__ att_out) {
    const int slot = blockIdx.x >> 4;
    const int h = blockIdx.x & 15;
    const int b = blockIdx.y;
    const int qt = (slot < 16) ? (31 - slot) : (slot - 16);
    const int tid = threadIdx.x;
    const int w = tid >> 6, lane = tid & 63;
    const int lrow = lane & 15, g = lane >> 4;
    const int pw = w >> 1;       // parity this wave computes
    const int rh = w & 1;        // row-half: rows rh*32 + [0,32)

    __shared__ __align__(16) u16 Ks[2][64 * 64];
    __shared__ __align__(16) u16 Vts[2][64 * 64];

    const u16* kg_base = &Kb[((size_t)b * NH + h) * TT * DD];
    const u16* vg_base = &Vtb[((size_t)b * NH + h) * DD * TT];

    auto STAGE = [&](int bufi, int kt) {
#pragma unroll
        for (int i = 0; i < 2; ++i) {
            int e = i * 2048 + tid * 8;
            int r = e >> 6, c = e & 63;
            int cs = c ^ ((r & 7) << 3);  // u16 units, keeps 16B alignment
            gload_lds16(kg_base + (size_t)kt * 64 * DD + r * DD + cs,
                        (char*)Ks[bufi] + i * 4096 + w * 1024);
            gload_lds16(vg_base + kt * 64 + (size_t)r * TT + cs,
                        (char*)Vts[bufi] + i * 4096 + w * 1024);
        }
    };

    const int qr0 = qt * 64 + rh * 32 + lrow;       // group-0 softmax row
    const int qr1 = qr0 + 16;                       // group-1 softmax row
    const int rswz = (lrow & 7) << 4;               // read-side byte swizzle

    bf16x8 qf0[2], qf1[2];
#pragma unroll
    for (int kk = 0; kk < 2; ++kk) {
        qf0[kk] = *reinterpret_cast<const bf16x8*>(
            &Qb[(((size_t)b * NH + h) * TT + qr0) * DD + kk * 32 + g * 8]);
        qf1[kk] = *reinterpret_cast<const bf16x8*>(
            &Qb[(((size_t)b * NH + h) * TT + qr1) * DD + kk * 32 + g * 8]);
    }

    f32x4 oacc0[4] = {}, oacc1[4] = {};
    float lp0 = 0.f, lp1 = 0.f;

    const unsigned char* mrow0 = mb + ((size_t)h * TT + qr0) * (TT / 8);
    const unsigned char* mrow1 = mb + ((size_t)h * TT + qr1) * (TT / 8);

    STAGE(0, 0);
    int buf = 0;

#pragma unroll 1
    for (int kt = 0; kt <= qt; ++kt) {
        u64 mw0 = *reinterpret_cast<const u64*>(mrow0 + kt * 8);
        u64 mw1 = *reinterpret_cast<const u64*>(mrow1 + kt * 8);
        // drain own stage(kt) loads; the 2 mask loads stay in flight.
        asm volatile("s_waitcnt vmcnt(2)" ::: "memory");
        __builtin_amdgcn_sched_barrier(0);
        asm volatile("s_barrier" ::: "memory");
        if (kt < qt) STAGE(buf ^ 1, kt + 1);

        if ((kt & 1) == pw) {
            // ---- S^T = K Q^T for both groups, K fragment read ONCE ----
            f32x4 s0[4] = {}, s1[4] = {};
            __builtin_amdgcn_s_setprio(1);
#pragma unroll
            for (int kk = 0; kk < 2; ++kk)
#pragma unroll
                for (int nt = 0; nt < 4; ++nt) {
                    bf16x8 kf = *reinterpret_cast<const bf16x8*>(
                        (char*)Ks[buf] + (((nt * 16 + lrow) * 128 + (kk * 32 + g * 8) * 2) ^ rswz));
                    s0[nt] = __builtin_amdgcn_mfma_f32_16x16x32_bf16(kf, qf0[kk], s0[nt], 0, 0, 0);
                    s1[nt] = __builtin_amdgcn_mfma_f32_16x16x32_bf16(kf, qf1[kk], s1[nt], 0, 0, 0);
                }
            __builtin_amdgcn_s_setprio(0);

            // ---- P = exp2(S) & maskbit for both groups; pack in-register ----
            bf16x8 pf0[2], pf1[2];
            {
                u64 mws = mw0 >> (g * 4);
                u32 wlo = (u32)mws, whi = (u32)(mws >> 32);
#pragma unroll
                for (int nt = 0; nt < 4; ++nt)
#pragma unroll
                    for (int j = 0; j < 4; ++j) {
                        int bi = nt * 16 + j;
                        u32 word = (bi < 32) ? wlo : whi;
                        u32 pm = (u32)(((int)(word << (31 - (bi & 31)))) >> 31);
                        float p = __builtin_bit_cast(float,
                                  __builtin_bit_cast(u32, exp2f(s0[nt][j])) & pm);
                        lp0 += p;
                        s0[nt][j] = p;
                    }
                u32 X[4][2];
#pragma unroll
                for (int nt = 0; nt < 4; ++nt)
#pragma unroll
                    for (int t = 0; t < 2; ++t)
                        asm("v_cvt_pk_bf16_f32 %0, %1, %2"
                            : "=v"(X[nt][t]) : "v"(s0[nt][2 * t]), "v"(s0[nt][2 * t + 1]));
#pragma unroll
                for (int kk = 0; kk < 2; ++kk) {
                    u32 pwd[4];
#pragma unroll
                    for (int t = 0; t < 2; ++t) {
                        u32 a = X[2 * kk][t], b2 = X[2 * kk + 1][t];
                        asm("v_permlane32_swap_b32 %0, %1" : "+v"(a), "+v"(b2));
                        asm("v_permlane16_swap_b32 %0, %1" : "+v"(a), "+v"(b2));
                        pwd[t] = a;
                        pwd[t + 2] = b2;
                    }
                    u32x4 wv = {pwd[0], pwd[1], pwd[2], pwd[3]};
                    pf0[kk] = __builtin_bit_cast(bf16x8, wv);
                }
            }
            {
                u64 mws = mw1 >> (g * 4);
                u32 wlo = (u32)mws, whi = (u32)(mws >> 32);
#pragma unroll
                for (int nt = 0; nt < 4; ++nt)
#pragma unroll
                    for (int j = 0; j < 4; ++j) {
                        int bi = nt * 16 + j;
                        u32 word = (bi < 32) ? wlo : whi;
                        u32 pm = (u32)(((int)(word << (31 - (bi & 31)))) >> 31);
                        float p = __builtin_bit_cast(float,
                                  __builtin_bit_cast(u32, exp2f(s1[nt][j])) & pm);
                        lp1 += p;
                        s1[nt][j] = p;
                    }
                u32 X[4][2];
#pragma unroll
                for (int nt = 0; nt < 4; ++nt)
#pragma unroll
                    for (int t = 0; t < 2; ++t)
                        asm("v_cvt_pk_bf16_f32 %0, %1, %2"
                            : "=v"(X[nt][t]) : "v"(s1[nt][2 * t]), "v"(s1[nt][2 * t + 1]));
#pragma unroll
                for (int kk = 0; kk < 2; ++kk) {
                    u32 pwd[4];
#pragma unroll
                    for (int t = 0; t < 2; ++t) {
                        u32 a = X[2 * kk][t], b2 = X[2 * kk + 1][t];
                        asm("v_permlane32_swap_b32 %0, %1" : "+v"(a), "+v"(b2));
                        asm("v_permlane16_swap_b32 %0, %1" : "+v"(a), "+v"(b2));
                        pwd[t] = a;
                        pwd[t + 2] = b2;
                    }
                    u32x4 wv = {pwd[0], pwd[1], pwd[2], pwd[3]};
                    pf1[kk] = __builtin_bit_cast(bf16x8, wv);
                }
            }

            // ---- O += P @ V for both groups, V fragment read ONCE ----
            __builtin_amdgcn_s_setprio(1);
#pragma unroll
            for (int kk = 0; kk < 2; ++kk)
#pragma unroll
                for (int dt = 0; dt < 4; ++dt) {
                    bf16x8 vf = *reinterpret_cast<const bf16x8*>(
                        (char*)Vts[buf] + (((dt * 16 + lrow) * 128 + (kk * 32 + g * 8) * 2) ^ rswz));
                    oacc0[dt] = __builtin_amdgcn_mfma_f32_16x16x32_bf16(pf0[kk], vf, oacc0[dt], 0, 0, 0);
                    oacc1[dt] = __builtin_amdgcn_mfma_f32_16x16x32_bf16(pf1[kk], vf, oacc1[dt], 0, 0, 0);
                }
            __builtin_amdgcn_s_setprio(0);
        }

        buf ^= 1;
    }

    // ---- combine parity partials: waves 2,3 -> LDS; waves 0,1 add ----------
    __syncthreads();  // all staging/reads done; Ks/Vts reusable
    char* cb = (rh == 0) ? (char*)Ks : (char*)Vts;  // 16 KB each, need 9.2 KB
    if (pw == 1) {
#pragma unroll
        for (int dt = 0; dt < 4; ++dt) {
            *reinterpret_cast<f32x4*>(cb + lane * 144 + dt * 16) = oacc0[dt];
            *reinterpret_cast<f32x4*>(cb + lane * 144 + 64 + dt * 16) = oacc1[dt];
        }
        *reinterpret_cast<float2*>(cb + lane * 144 + 128) = {lp0, lp1};
    }
    __syncthreads();
    if (pw == 1) return;

#pragma unroll
    for (int dt = 0; dt < 4; ++dt) {
        oacc0[dt] += *reinterpret_cast<const f32x4*>(cb + lane * 144 + dt * 16);
        oacc1[dt] += *reinterpret_cast<const f32x4*>(cb + lane * 144 + 64 + dt * 16);
    }
    float2 lp = *reinterpret_cast<const float2*>(cb + lane * 144 + 128);
    lp0 += lp.x;
    lp1 += lp.y;

    // ---- epilogue: l reductions, normalize + store bf16 [B,T,C] ----
    float l0 = lp0, l1 = lp1;
    l0 += __shfl_xor(l0, 16); l0 += __shfl_xor(l0, 32);
    l1 += __shfl_xor(l1, 16); l1 += __shfl_xor(l1, 32);
    float lb0[4], lb1[4];
#pragma unroll
    for (int j = 0; j < 4; ++j) {
        lb0[j] = __shfl(l0, (lane & 48) + g * 4 + j);
        lb1[j] = __shfl(l1, (lane & 48) + g * 4 + j);
    }
#pragma unroll
    for (int dt = 0; dt < 4; ++dt)
#pragma unroll
        for (int j = 0; j < 4; ++j) {
            int t0 = qt * 64 + rh * 32 + g * 4 + j;
            att_out[((size_t)b * TT + t0) * CC + h * DD + dt * 16 + lrow] =
                bf16bits(oacc0[dt][j] / lb0[j]);
            att_out[((size_t)b * TT + t0 + 16) * CC + h * DD + dt * 16 + lrow] =
                bf16bits(oacc1[dt][j] / lb1[j]);
        }
}

extern "C" void kernel_launch(void* const* d_in, const int* in_sizes, int n_in,
                              void* d_out, int out_size, void* d_ws, size_t ws_size,
                              hipStream_t stream) {
    const float* x = (const float*)d_in[0];
    const float* mask_logits = (const float*)d_in[1];
    const float* W_attn = (const float*)d_in[2];
    const float* b_attn = (const float*)d_in[3];
    const float* W_proj = (const float*)d_in[4];
    const float* b_proj = (const float*)d_in[5];
    float* out = (float*)d_out;

    char* ws = (char*)d_ws;
    u16* xb  = (u16*)(ws + 0);            // 8 MB — dead after QKV gemm
    u16* Wa  = (u16*)(ws + (8u << 20));   // 6 MB
    u16* Wp  = (u16*)(ws + (14u << 20));  // 2 MB
    u16* Qb  = (u16*)(ws + (16u << 20));  // 8 MB  [B,H,T,D]
    u16* Kb  = (u16*)(ws + (24u << 20));  // 8 MB  [B,H,T,D]
    u16* Vtb = (u16*)(ws + (32u << 20));  // 8 MB  [B,H,D,T]
    u16* att = (u16*)(ws + (40u << 20));  // 8 MB  [B,T,C]
    unsigned char* mbits = (unsigned char*)(ws + (48u << 20));  // 8 MB

    prep_all<<<1536, 256, 0, stream>>>(x, W_attn, W_proj, mask_logits,
                                       xb, Wa, Wp, mbits);
    gemm_qkv<<<dim3(24, 32), 256, 0, stream>>>(xb, Wa, b_attn, Qb, Kb, Vtb);
    attn_kernel<<<dim3(512, 2), 256, 0, stream>>>(Qb, Kb, Vtb, mbits, att);
    gemm_proj<<<dim3(8, 64), 256, 0, stream>>>(att, Wp, b_proj, out);
}

// Round 26
// 150.020 us; speedup vs baseline: 1.2419x; 1.2419x over previous
//
#include <hip/hip_runtime.h>
#include <hip/hip_bf16.h>
#include <stdint.h>

typedef unsigned short u16;
typedef unsigned int u32;
typedef unsigned long long u64;
typedef __attribute__((ext_vector_type(8))) short bf16x8;
typedef __attribute__((ext_vector_type(4))) float f32x4;
typedef __attribute__((ext_vector_type(4))) u32 u32x4;

#define NB 2
#define NH 16
#define TT 2048
#define DD 64
#define CC 1024

__device__ __forceinline__ u16 bf16bits(float f) {
    __hip_bfloat16 h = __float2bfloat16(f);
    return __builtin_bit_cast(unsigned short, h);
}

__device__ __forceinline__ void gload_lds16(const void* g, void* l) {
    __builtin_amdgcn_global_load_lds(
        (const __attribute__((address_space(1))) void*)g,
        (__attribute__((address_space(3))) void*)l, 16, 0, 0);
}

// ---------------- fused prep: f32->bf16 converts + causal-clipped mask bits --
__global__ __launch_bounds__(256) void prep_all(
    const float* __restrict__ x, const float* __restrict__ Wa_f,
    const float* __restrict__ Wp_f, const float* __restrict__ ml,
    u16* __restrict__ xb, u16* __restrict__ wab, u16* __restrict__ wpb,
    unsigned char* __restrict__ mb) {
    const int bid = blockIdx.x;
    if (bid < 512) {
        int idx = bid * 256 + threadIdx.x;
        for (int i = idx; i < 2097152; i += 512 * 256) {
            const float* src; u16* dst; int off;
            if (i < 1048576)      { src = x;    dst = xb;  off = i; }
            else if (i < 1835008) { src = Wa_f; dst = wab; off = i - 1048576; }
            else                  { src = Wp_f; dst = wpb; off = i - 1835008; }
            float4 v = reinterpret_cast<const float4*>(src)[off];
            ushort4 o;
            o.x = bf16bits(v.x); o.y = bf16bits(v.y);
            o.z = bf16bits(v.z); o.w = bf16bits(v.w);
            reinterpret_cast<ushort4*>(dst)[off] = o;
        }
    } else {
        const int wid = ((bid - 512) << 2) + (threadIdx.x >> 6);  // 0..4095
        const int lane = threadIdx.x & 63;
        const int i0 = wid & 2047;
        const int hbase = (wid >> 11) << 3;  // 0 or 8
#pragma unroll 1
        for (int k = 0; k < 8; ++k) {
            int h = hbase + k;
            int i = (k & 1) ? (2047 - i0) : i0;
            int row = h * 2048 + i;
            const float* src = ml + (size_t)row * TT;
            unsigned char* dst = mb + (size_t)row * (TT / 8);
#pragma unroll 1
            for (int c8 = lane; c8 < 256; c8 += 64) {
                unsigned char v = 0;
                if (c8 * 8 <= i) {
                    const float4* p = reinterpret_cast<const float4*>(src + c8 * 8);
                    float4 a = p[0];
                    float4 b = p[1];
                    unsigned u = 0;
                    u |= (a.x > 0.f) ? 1u : 0u;
                    u |= (a.y > 0.f) ? 2u : 0u;
                    u |= (a.z > 0.f) ? 4u : 0u;
                    u |= (a.w > 0.f) ? 8u : 0u;
                    u |= (b.x > 0.f) ? 16u : 0u;
                    u |= (b.y > 0.f) ? 32u : 0u;
                    u |= (b.z > 0.f) ? 64u : 0u;
                    u |= (b.w > 0.f) ? 128u : 0u;
                    int rem = i - c8 * 8;
                    if (rem < 7) u &= (1u << (rem + 1)) - 1;  // causal clip
                    v = (unsigned char)u;
                }
                dst[c8] = v;
            }
        }
    }
}

// ---------------- QKV GEMM (128x128 tile) ------------------------------------
__global__ __launch_bounds__(256) void gemm_qkv(
    const u16* __restrict__ A, const u16* __restrict__ Bw,
    const float* __restrict__ bias,
    u16* __restrict__ Qb, u16* __restrict__ Kb, u16* __restrict__ Vtb) {
    const int bm = blockIdx.y * 128;
    const int bn = blockIdx.x * 128;
    const int tid = threadIdx.x;
    const int w = tid >> 6, lane = tid & 63;
    const int lrow = lane & 15, lgrp = lane >> 4;
    const int wr = (w >> 1) * 64, wc = (w & 1) * 64;

    __shared__ __align__(16) u16 ABs[2][128 * 64];
    u16* As = ABs[0];
    u16* Bs = ABs[1];

    f32x4 acc[4][4] = {};

    for (int kt = 0; kt < 16; ++kt) {
        const int k0 = kt << 6;
#pragma unroll
        for (int i = 0; i < 4; ++i) {
            int e = i * 2048 + tid * 8;
            int r = e >> 6, c = e & 63;
            gload_lds16(A + (size_t)(bm + r) * CC + k0 + c, (char*)As + i * 4096 + w * 1024);
            gload_lds16(Bw + (size_t)(bn + r) * CC + k0 + c, (char*)Bs + i * 4096 + w * 1024);
        }
        __syncthreads();
#pragma unroll
        for (int kk = 0; kk < 2; ++kk) {
            bf16x8 af[4], bfz[4];
#pragma unroll
            for (int i = 0; i < 4; ++i)
                af[i] = *reinterpret_cast<const bf16x8*>(&As[(wr + i * 16 + lrow) * 64 + kk * 32 + lgrp * 8]);
#pragma unroll
            for (int i = 0; i < 4; ++i)
                bfz[i] = *reinterpret_cast<const bf16x8*>(&Bs[(wc + i * 16 + lrow) * 64 + kk * 32 + lgrp * 8]);
#pragma unroll
            for (int mi = 0; mi < 4; ++mi)
#pragma unroll
                for (int ni = 0; ni < 4; ++ni)
                    acc[mi][ni] = __builtin_amdgcn_mfma_f32_16x16x32_bf16(af[mi], bfz[ni], acc[mi][ni], 0, 0, 0);
        }
        __syncthreads();
    }

    const int sec = bn >> 10;

    if (sec == 2) {
        // ---- V epilogue: LDS transpose for coalesced Vt writes ----
        u16* Tl = &ABs[0][0];
#pragma unroll
        for (int ni = 0; ni < 4; ++ni) {
            int nl = wc + ni * 16 + lrow;
            float bv = bias[bn + nl];
#pragma unroll
            for (int mi = 0; mi < 4; ++mi) {
                int ml2 = wr + mi * 16 + lgrp * 4;
                u64 pk = 0;
#pragma unroll
                for (int j = 0; j < 4; ++j)
                    pk |= (u64)bf16bits(acc[mi][ni][j] + bv) << (16 * j);
                int byte = nl * 256 + ((ml2 * 2) ^ ((nl & 7) << 4));
                *reinterpret_cast<u64*>((char*)Tl + byte) = pk;
            }
        }
        __syncthreads();
        int r = tid >> 1, half = tid & 1;
        int h = ((bn & 1023) >> 6) + (r >> 6);
        int d = r & 63;
        int b = bm >> 11;
        u16* gdst = Vtb + (((size_t)b * NH + h) * DD + d) * TT + (bm & 2047) + half * 64;
#pragma unroll
        for (int c = 0; c < 8; ++c) {
            uint4 v = *reinterpret_cast<const uint4*>(
                (char*)Tl + r * 256 + ((half * 128 + c * 16) ^ ((r & 7) << 4)));
            *reinterpret_cast<uint4*>(gdst + c * 8) = v;
        }
        return;
    }

#pragma unroll
    for (int ni = 0; ni < 4; ++ni) {
        int n = bn + wc + ni * 16 + lrow;
        float bv = bias[n];
#pragma unroll
        for (int mi = 0; mi < 4; ++mi) {
#pragma unroll
            for (int j = 0; j < 4; ++j) {
                int m = bm + wr + mi * 16 + lgrp * 4 + j;
                float v = acc[mi][ni][j] + bv;
                int h = (n & 1023) >> 6;
                int d = n & 63;
                int b = m >> 11;
                int t = m & 2047;
                if (sec == 0) {
                    // fold 1/sqrt(64) and log2(e): softmax runs in exp2 domain
                    Qb[(((size_t)b * NH + h) * TT + t) * DD + d] =
                        bf16bits(v * (0.125f * 1.4426950408889634f));
                } else {
                    Kb[(((size_t)b * NH + h) * TT + t) * DD + d] = bf16bits(v);
                }
            }
        }
    }
}

// ---------------- proj GEMM (64x128 tile, 512 blocks = 2/CU) -----------------
__global__ __launch_bounds__(256) void gemm_proj(
    const u16* __restrict__ A, const u16* __restrict__ Bw,
    const float* __restrict__ bias, float* __restrict__ Cout) {
    const int bm = blockIdx.y * 64;
    const int bn = blockIdx.x * 128;
    const int tid = threadIdx.x;
    const int w = tid >> 6, lane = tid & 63;
    const int lrow = lane & 15, lgrp = lane >> 4;
    const int wr = (w >> 1) * 32, wc = (w & 1) * 64;

    __shared__ __align__(16) u16 As[64 * 64];    // 8 KB
    __shared__ __align__(16) u16 Bs[128 * 64];   // 16 KB

    f32x4 acc[2][4] = {};

    for (int kt = 0; kt < 16; ++kt) {
        const int k0 = kt << 6;
#pragma unroll
        for (int i = 0; i < 2; ++i) {
            int e = i * 2048 + tid * 8;
            int r = e >> 6, c = e & 63;
            gload_lds16(A + (size_t)(bm + r) * CC + k0 + c, (char*)As + i * 4096 + w * 1024);
        }
#pragma unroll
        for (int i = 0; i < 4; ++i) {
            int e = i * 2048 + tid * 8;
            int r = e >> 6, c = e & 63;
            gload_lds16(Bw + (size_t)(bn + r) * CC + k0 + c, (char*)Bs + i * 4096 + w * 1024);
        }
        __syncthreads();
#pragma unroll
        for (int kk = 0; kk < 2; ++kk) {
            bf16x8 af[2], bfz[4];
#pragma unroll
            for (int i = 0; i < 2; ++i)
                af[i] = *reinterpret_cast<const bf16x8*>(&As[(wr + i * 16 + lrow) * 64 + kk * 32 + lgrp * 8]);
#pragma unroll
            for (int i = 0; i < 4; ++i)
                bfz[i] = *reinterpret_cast<const bf16x8*>(&Bs[(wc + i * 16 + lrow) * 64 + kk * 32 + lgrp * 8]);
#pragma unroll
            for (int mi = 0; mi < 2; ++mi)
#pragma unroll
                for (int ni = 0; ni < 4; ++ni)
                    acc[mi][ni] = __builtin_amdgcn_mfma_f32_16x16x32_bf16(af[mi], bfz[ni], acc[mi][ni], 0, 0, 0);
        }
        __syncthreads();
    }

#pragma unroll
    for (int ni = 0; ni < 4; ++ni) {
        int n = bn + wc + ni * 16 + lrow;
        float bv = bias[n];
#pragma unroll
        for (int mi = 0; mi < 2; ++mi) {
#pragma unroll
            for (int j = 0; j < 4; ++j) {
                int m = bm + wr + mi * 16 + lgrp * 4 + j;
                Cout[(size_t)m * 1024 + n] = acc[mi][ni][j] + bv;
            }
        }
    }
}

// ---------------- fused masked flash attention (r24 winner) ------------------
// T12: P redistribution fully in-register (cvt_pk + permlane32/16_swap), no Ps
// LDS buffer. Single-barrier tile loop, counted vmcnt, causal pre-baked mask,
// deferred l reduction.
// grid: (512 = slot*16+h, 2 batches); block 256 = 4 waves, one 64-row q-tile.
__global__ __launch_bounds__(256) void attn_kernel(
    const u16* __restrict__ Qb, const u16* __restrict__ Kb,
    const u16* __restrict__ Vtb, const unsigned char* __restrict__ mb,
    u16* __restrict__ att_out) {
    const int slot = blockIdx.x >> 4;
    const int h = blockIdx.x & 15;
    const int b = blockIdx.y;
    const int qt = (slot < 16) ? (31 - slot) : (slot - 16);
    const int tid = threadIdx.x;
    const int w = tid >> 6, lane = tid & 63;
    const int lrow = lane & 15, g = lane >> 4;

    __shared__ __align__(16) u16 Ks[2][64 * 64];
    __shared__ __align__(16) u16 Vts[2][64 * 64];

    const u16* kg_base = &Kb[((size_t)b * NH + h) * TT * DD];
    const u16* vg_base = &Vtb[((size_t)b * NH + h) * DD * TT];

    auto STAGE = [&](int bufi, int kt) {
#pragma unroll
        for (int i = 0; i < 2; ++i) {
            int e = i * 2048 + tid * 8;
            int r = e >> 6, c = e & 63;
            int cs = c ^ ((r & 7) << 3);  // u16 units, keeps 16B alignment
            gload_lds16(kg_base + (size_t)kt * 64 * DD + r * DD + cs,
                        (char*)Ks[bufi] + i * 4096 + w * 1024);
            gload_lds16(vg_base + kt * 64 + (size_t)r * TT + cs,
                        (char*)Vts[bufi] + i * 4096 + w * 1024);
        }
    };

    const int qrow_g = qt * 64 + w * 16 + lrow;  // this lane's softmax row
    const int rswz = (lrow & 7) << 4;            // read-side byte swizzle

    bf16x8 qf[2];
#pragma unroll
    for (int kk = 0; kk < 2; ++kk)
        qf[kk] = *reinterpret_cast<const bf16x8*>(
            &Qb[(((size_t)b * NH + h) * TT + qrow_g) * DD + kk * 32 + g * 8]);

    f32x4 oacc[4] = {};          // O[qr = g*4+j][d = dt*16+lrow]
    float l_part = 0.f;          // per-lane partial; cross-lane reduce deferred

    const unsigned char* mrow_base = mb + ((size_t)h * TT + qrow_g) * (TT / 8);

    STAGE(0, 0);
    int buf = 0;

#pragma unroll 1
    for (int kt = 0; kt <= qt; ++kt) {
        u64 mw = *reinterpret_cast<const u64*>(mrow_base + kt * 8);
        // drain own stage(kt) loads; mask load stays in flight.
        asm volatile("s_waitcnt vmcnt(1)" ::: "memory");
        __builtin_amdgcn_sched_barrier(0);
        asm volatile("s_barrier" ::: "memory");
        if (kt < qt) STAGE(buf ^ 1, kt + 1);

        // ---- S^T = K Q^T (exp2 domain): lane holds S[qrow_g][16 cols] ----
        f32x4 s[4] = {};
        __builtin_amdgcn_s_setprio(1);
#pragma unroll
        for (int kk = 0; kk < 2; ++kk)
#pragma unroll
            for (int nt = 0; nt < 4; ++nt) {
                bf16x8 kf = *reinterpret_cast<const bf16x8*>(
                    (char*)Ks[buf] + (((nt * 16 + lrow) * 128 + (kk * 32 + g * 8) * 2) ^ rswz));
                s[nt] = __builtin_amdgcn_mfma_f32_16x16x32_bf16(kf, qf[kk], s[nt], 0, 0, 0);
            }
        __builtin_amdgcn_s_setprio(0);

        // ---- P = exp2(S) & signext(maskbit)  (uniform path; causal pre-baked)
        u64 mws = mw >> (g * 4);
        u32 wlo = (u32)mws, whi = (u32)(mws >> 32);
#pragma unroll
        for (int nt = 0; nt < 4; ++nt)
#pragma unroll
            for (int j = 0; j < 4; ++j) {
                int bi = nt * 16 + j;
                u32 word = (bi < 32) ? wlo : whi;
                u32 pm = (u32)(((int)(word << (31 - (bi & 31)))) >> 31);  // 0 / ~0
                float p = __builtin_bit_cast(float,
                          __builtin_bit_cast(u32, exp2f(s[nt][j])) & pm);
                l_part += p;
                s[nt][j] = p;
            }

        // ---- pack P words: X[nt][t] = bf16x2(cols nt*16+4g+2t, +1) ----
        u32 X[4][2];
#pragma unroll
        for (int nt = 0; nt < 4; ++nt)
#pragma unroll
            for (int t = 0; t < 2; ++t)
                asm("v_cvt_pk_bf16_f32 %0, %1, %2"
                    : "=v"(X[nt][t]) : "v"(s[nt][2 * t]), "v"(s[nt][2 * t + 1]));

        // ---- in-register redistribution -> PV A-fragments ----
        bf16x8 pf[2];
#pragma unroll
        for (int kk = 0; kk < 2; ++kk) {
            u32 pw[4];
#pragma unroll
            for (int t = 0; t < 2; ++t) {
                u32 a = X[2 * kk][t], b2 = X[2 * kk + 1][t];
                asm("v_permlane32_swap_b32 %0, %1" : "+v"(a), "+v"(b2));
                asm("v_permlane16_swap_b32 %0, %1" : "+v"(a), "+v"(b2));
                pw[t] = a;        // word t   (rows: X@0, X@2, X'@0, X'@2)
                pw[t + 2] = b2;   // word t+2 (rows: X@1, X@3, X'@1, X'@3)
            }
            u32x4 wv = {pw[0], pw[1], pw[2], pw[3]};
            pf[kk] = __builtin_bit_cast(bf16x8, wv);
        }

        // ---- O += P @ V ----
        __builtin_amdgcn_s_setprio(1);
#pragma unroll
        for (int kk = 0; kk < 2; ++kk)
#pragma unroll
            for (int dt = 0; dt < 4; ++dt) {
                bf16x8 vf = *reinterpret_cast<const bf16x8*>(
                    (char*)Vts[buf] + (((dt * 16 + lrow) * 128 + (kk * 32 + g * 8) * 2) ^ rswz));
                oacc[dt] = __builtin_amdgcn_mfma_f32_16x16x32_bf16(pf[kk], vf, oacc[dt], 0, 0, 0);
            }
        __builtin_amdgcn_s_setprio(0);

        buf ^= 1;
    }

    // ---- epilogue: deferred l reduction, normalize + store bf16 [B,T,C] ----
    float l_run = l_part;
    l_run += __shfl_xor(l_run, 16);
    l_run += __shfl_xor(l_run, 32);
    float lb[4];
#pragma unroll
    for (int j = 0; j < 4; ++j)
        lb[j] = __shfl(l_run, (lane & 48) + g * 4 + j);
#pragma unroll
    for (int dt = 0; dt < 4; ++dt)
#pragma unroll
        for (int j = 0; j < 4; ++j) {
            int t = qt * 64 + w * 16 + g * 4 + j;
            float o = oacc[dt][j] / lb[j];
            att_out[((size_t)b * TT + t) * CC + h * DD + dt * 16 + lrow] = bf16bits(o);
        }
}

extern "C" void kernel_launch(void* const* d_in, const int* in_sizes, int n_in,
                              void* d_out, int out_size, void* d_ws, size_t ws_size,
                              hipStream_t stream) {
    const float* x = (const float*)d_in[0];
    const float* mask_logits = (const float*)d_in[1];
    const float* W_attn = (const float*)d_in[2];
    const float* b_attn = (const float*)d_in[3];
    const float* W_proj = (const float*)d_in[4];
    const float* b_proj = (const float*)d_in[5];
    float* out = (float*)d_out;

    char* ws = (char*)d_ws;
    u16* xb  = (u16*)(ws + 0);            // 8 MB — dead after QKV gemm
    u16* Wa  = (u16*)(ws + (8u << 20));   // 6 MB
    u16* Wp  = (u16*)(ws + (14u << 20));  // 2 MB
    u16* Qb  = (u16*)(ws + (16u << 20));  // 8 MB  [B,H,T,D]
    u16* Kb  = (u16*)(ws + (24u << 20));  // 8 MB  [B,H,T,D]
    u16* Vtb = (u16*)(ws + (32u << 20));  // 8 MB  [B,H,D,T]
    u16* att = (u16*)(ws + (40u << 20));  // 8 MB  [B,T,C]
    unsigned char* mbits = (unsigned char*)(ws + (48u << 20));  // 8 MB

    prep_all<<<1536, 256, 0, stream>>>(x, W_attn, W_proj, mask_logits,
                                       xb, Wa, Wp, mbits);
    gemm_qkv<<<dim3(24, 32), 256, 0, stream>>>(xb, Wa, b_attn, Qb, Kb, Vtb);
    attn_kernel<<<dim3(512, 2), 256, 0, stream>>>(Qb, Kb, Vtb, mbits, att);
    gemm_proj<<<dim3(8, 64), 256, 0, stream>>>(att, Wp, b_proj, out);
}